// Round 1
// baseline (621.112 us; speedup 1.0000x reference)
//
#include <hip/hip_runtime.h>

#define CH 64
#define HW 4096
#define NN 2048

// ---------------- conv1 (128->64 1x1) + bias -> z ----------------
__global__ __launch_bounds__(256) void k_conv1(const float* __restrict__ x,
    const float* __restrict__ y, const float* __restrict__ w,
    const float* __restrict__ bias, float* __restrict__ z) {
  __shared__ float wl[128][64];  // [c][o]
  int t = threadIdx.x;
  for (int i = t; i < 8192; i += 256) { int o = i >> 7, c = i & 127; wl[c][o] = w[i]; }
  __syncthreads();
  int blk = blockIdx.x; int b = blk >> 4; int s = ((blk & 15) << 8) + t;
  const float* xb = x + b * (CH * HW) + s;
  const float* yb = y + b * (CH * HW) + s;
  float acc[64];
#pragma unroll
  for (int o = 0; o < 64; ++o) acc[o] = 0.f;
  for (int c = 0; c < 64; ++c) {
    float xv = xb[c * HW];
    float yv = yb[c * HW];
    const float4* wx = reinterpret_cast<const float4*>(&wl[c][0]);
    const float4* wy = reinterpret_cast<const float4*>(&wl[c + 64][0]);
#pragma unroll
    for (int o4 = 0; o4 < 16; ++o4) {
      float4 a = wx[o4], bb = wy[o4];
      acc[4 * o4 + 0] += xv * a.x + yv * bb.x;
      acc[4 * o4 + 1] += xv * a.y + yv * bb.y;
      acc[4 * o4 + 2] += xv * a.z + yv * bb.z;
      acc[4 * o4 + 3] += xv * a.w + yv * bb.w;
    }
  }
  float* zb = z + b * (CH * HW) + s;
#pragma unroll
  for (int o = 0; o < 64; ++o) zb[o * HW] = acc[o] + bias[o];
}

// ---------------- BN2d stats per channel ----------------
__global__ __launch_bounds__(256) void k_bnstats(const float* __restrict__ z,
    float* __restrict__ meanp, float* __restrict__ istdp) {
  int c = blockIdx.x;
  int t = threadIdx.x;
  float s = 0.f, s2 = 0.f;
  for (int b = 0; b < 8; ++b) {
    const float* p = z + b * (CH * HW) + c * HW;
    for (int i = t; i < HW; i += 256) { float v = p[i]; s += v; s2 += v * v; }
  }
  for (int off = 32; off; off >>= 1) { s += __shfl_xor(s, off); s2 += __shfl_xor(s2, off); }
  __shared__ float rs[4], rs2[4];
  int wid = t >> 6;
  if ((t & 63) == 0) { rs[wid] = s; rs2[wid] = s2; }
  __syncthreads();
  if (t == 0) {
    float S = rs[0] + rs[1] + rs[2] + rs[3];
    float S2 = rs2[0] + rs2[1] + rs2[2] + rs2[3];
    float mean = S / 32768.f;
    float var = S2 / 32768.f - mean * mean;
    meanp[c] = mean;
    istdp[c] = rsqrtf(var + 1e-5f);
  }
}

// ---------------- phi/theta/g projections with BN folded in ----------------
__global__ __launch_bounds__(256) void k_proj(const float* __restrict__ z,
    const float* __restrict__ phw, const float* __restrict__ thw,
    const float* __restrict__ gw, const float* __restrict__ meanp,
    const float* __restrict__ istdp, const float* __restrict__ g1,
    const float* __restrict__ b1, float* __restrict__ phi,
    float* __restrict__ theta, float* __restrict__ gout) {
  __shared__ float effw[3][64][32];  // [p][c][ic]
  __shared__ float effb[3][32];
  __shared__ float sc[64], sh[64];
  int t = threadIdx.x;
  if (t < 64) { float s_ = g1[t] * istdp[t]; sc[t] = s_; sh[t] = b1[t] - meanp[t] * s_; }
  __syncthreads();
  for (int i = t; i < 3 * 2048; i += 256) {
    int p = i >> 11; int r = i & 2047; int ic = r >> 6; int c = r & 63;
    const float* wp = (p == 0) ? phw : (p == 1) ? thw : gw;
    effw[p][c][ic] = wp[ic * 64 + c] * sc[c];
  }
  if (t < 96) {
    int p = t / 32, ic = t % 32;
    const float* wp = (p == 0) ? phw : (p == 1) ? thw : gw;
    float s_ = 0.f;
    for (int c = 0; c < 64; ++c) s_ += wp[ic * 64 + c] * sh[c];
    effb[p][ic] = s_;
  }
  __syncthreads();
  int blk = blockIdx.x; int b = blk >> 4; int s = ((blk & 15) << 8) + t;
  const float* zb = z + b * (CH * HW) + s;
  for (int p = 0; p < 3; ++p) {
    float acc[32];
#pragma unroll
    for (int ic = 0; ic < 32; ++ic) acc[ic] = 0.f;
    for (int c = 0; c < 64; ++c) {
      float v = zb[c * HW];
      const float4* w4 = reinterpret_cast<const float4*>(&effw[p][c][0]);
#pragma unroll
      for (int q = 0; q < 8; ++q) {
        float4 wv = w4[q];
        acc[4 * q + 0] += v * wv.x;
        acc[4 * q + 1] += v * wv.y;
        acc[4 * q + 2] += v * wv.z;
        acc[4 * q + 3] += v * wv.w;
      }
    }
    float* ob = ((p == 0) ? phi : (p == 1) ? theta : gout) + b * (32 * HW) + s;
#pragma unroll
    for (int ic = 0; ic < 32; ++ic) ob[ic * HW] = acc[ic] + effb[p][ic];
  }
}

// ---------------- pass A: reciprocal column sums of exp(attn) ----------------
__global__ __launch_bounds__(256) void k_colsum(const float* __restrict__ phi,
    const float* __restrict__ theta, float* __restrict__ rcs) {
  int blk = blockIdx.x; int b = blk >> 5; int m0 = (blk & 31) << 6;
  int t = threadIdx.x; int lane = t & 63; int grp = t >> 6;
  __shared__ float pl[64][64];  // [c][ml]
  __shared__ float tl[64][64];  // [c][nl]
  const float* pb = phi + b * (CH * NN);
  const float* tb = theta + b * (CH * NN);
#pragma unroll
  for (int k = 0; k < 16; ++k) {
    int c = grp * 16 + k;
    pl[c][lane] = pb[c * NN + m0 + lane];
  }
  float part[16];
#pragma unroll
  for (int j = 0; j < 16; ++j) part[j] = 0.f;
  for (int nt = 0; nt < 32; ++nt) {
    int n0 = nt << 6;
    __syncthreads();
#pragma unroll
    for (int k = 0; k < 16; ++k) {
      int c = grp * 16 + k;
      tl[c][lane] = tb[c * NN + n0 + lane];
    }
    __syncthreads();
    float a[16];
#pragma unroll
    for (int j = 0; j < 16; ++j) a[j] = 0.f;
    for (int c = 0; c < 64; ++c) {
      float tv = tl[c][lane];
      const float4* p4 = reinterpret_cast<const float4*>(&pl[c][grp * 16]);
#pragma unroll
      for (int j4 = 0; j4 < 4; ++j4) {
        float4 pv = p4[j4];
        a[4 * j4 + 0] += tv * pv.x;
        a[4 * j4 + 1] += tv * pv.y;
        a[4 * j4 + 2] += tv * pv.z;
        a[4 * j4 + 3] += tv * pv.w;
      }
    }
#pragma unroll
    for (int j = 0; j < 16; ++j) part[j] += __expf(a[j]);
  }
#pragma unroll
  for (int j = 0; j < 16; ++j) {
    float v = part[j];
    for (int off = 32; off; off >>= 1) v += __shfl_xor(v, off);
    if (lane == 0) rcs[b * NN + m0 + grp * 16 + j] = 1.0f / v;
  }
}

// ---------------- pass B: o = exp(attn) * (g/colsum), write [c][n] ----------------
__global__ __launch_bounds__(256) void k_pv(const float* __restrict__ phi,
    const float* __restrict__ theta, const float* __restrict__ gp,
    const float* __restrict__ rcs, float* __restrict__ obuf) {
  int blk = blockIdx.x; int b = blk >> 5; int n0 = (blk & 31) << 6;
  int t = threadIdx.x; int lane = t & 63; int grp = t >> 6;
  __shared__ float tl[64][64];  // [c][nl]
  __shared__ float pl[64][64];  // [c][ml]
  __shared__ float gl[64][68];  // [ml][c] pre-scaled by rcs (padded)
  __shared__ float ea[64][64];  // [ml][nl]
  const float* tb = theta + b * (CH * NN);
  const float* pb = phi + b * (CH * NN);
  const float* gb = gp + b * (CH * NN);
  const float* rb = rcs + b * NN;
#pragma unroll
  for (int k = 0; k < 16; ++k) {
    int c = grp * 16 + k;
    tl[c][lane] = tb[c * NN + n0 + lane];
  }
  float acc[16];
#pragma unroll
  for (int j = 0; j < 16; ++j) acc[j] = 0.f;
  for (int mt = 0; mt < 32; ++mt) {
    int m0 = mt << 6;
    __syncthreads();
    float r_ = rb[m0 + lane];
#pragma unroll
    for (int k = 0; k < 16; ++k) {
      int c = grp * 16 + k;
      pl[c][lane] = pb[c * NN + m0 + lane];
      gl[lane][c] = gb[c * NN + m0 + lane] * r_;
    }
    __syncthreads();
    float a[16];
#pragma unroll
    for (int j = 0; j < 16; ++j) a[j] = 0.f;
    for (int c = 0; c < 64; ++c) {
      float tv = tl[c][lane];
      const float4* p4 = reinterpret_cast<const float4*>(&pl[c][grp * 16]);
#pragma unroll
      for (int j4 = 0; j4 < 4; ++j4) {
        float4 pv = p4[j4];
        a[4 * j4 + 0] += tv * pv.x;
        a[4 * j4 + 1] += tv * pv.y;
        a[4 * j4 + 2] += tv * pv.z;
        a[4 * j4 + 3] += tv * pv.w;
      }
    }
#pragma unroll
    for (int j = 0; j < 16; ++j) ea[grp * 16 + j][lane] = __expf(a[j]);
    __syncthreads();
#pragma unroll 4
    for (int m = 0; m < 64; ++m) {
      float ev = ea[m][lane];
      const float4* g4 = reinterpret_cast<const float4*>(&gl[m][grp * 16]);
#pragma unroll
      for (int j4 = 0; j4 < 4; ++j4) {
        float4 gv = g4[j4];
        acc[4 * j4 + 0] += ev * gv.x;
        acc[4 * j4 + 1] += ev * gv.y;
        acc[4 * j4 + 2] += ev * gv.z;
        acc[4 * j4 + 3] += ev * gv.w;
      }
    }
  }
  float* ob = obuf + b * (CH * NN) + n0 + lane;
#pragma unroll
  for (int j = 0; j < 16; ++j) ob[(grp * 16 + j) * NN] = acc[j];
}

// ---------------- mask conv (32->64) + BN(z) residual, in-place into d_out ----------------
__global__ __launch_bounds__(256) void k_mask(const float* __restrict__ obuf,
    const float* __restrict__ mw, const float* __restrict__ meanp,
    const float* __restrict__ istdp, const float* __restrict__ g1,
    const float* __restrict__ b1, float* __restrict__ zio) {
  __shared__ float ml_[32][64];  // [ic][oc]
  __shared__ float sc[64], sh[64];
  int t = threadIdx.x;
  for (int i = t; i < 2048; i += 256) { int oc = i >> 5, ic = i & 31; ml_[ic][oc] = mw[i]; }
  if (t < 64) { float s_ = g1[t] * istdp[t]; sc[t] = s_; sh[t] = b1[t] - meanp[t] * s_; }
  __syncthreads();
  int blk = blockIdx.x; int b = blk >> 4; int s = ((blk & 15) << 8) + t;
  const float* ob = obuf + b * (32 * HW) + s;
  float acc[64];
#pragma unroll
  for (int o = 0; o < 64; ++o) acc[o] = 0.f;
  for (int ic = 0; ic < 32; ++ic) {
    float v = ob[ic * HW];
    const float4* w4 = reinterpret_cast<const float4*>(&ml_[ic][0]);
#pragma unroll
    for (int o4 = 0; o4 < 16; ++o4) {
      float4 wv = w4[o4];
      acc[4 * o4 + 0] += v * wv.x;
      acc[4 * o4 + 1] += v * wv.y;
      acc[4 * o4 + 2] += v * wv.z;
      acc[4 * o4 + 3] += v * wv.w;
    }
  }
  float* zb = zio + b * (CH * HW) + s;
#pragma unroll
  for (int oc = 0; oc < 64; ++oc) {
    float zv = zb[oc * HW];
    zb[oc * HW] = acc[oc] + sc[oc] * zv + sh[oc];
  }
}

// ---------------- adaptive avg pool per (b,c) ----------------
__global__ __launch_bounds__(256) void k_pool(const float* __restrict__ feasc,
    float* __restrict__ pool) {
  int bc = blockIdx.x;
  int t = threadIdx.x;
  const float* p = feasc + bc * HW;
  float s = 0.f;
  for (int i = t; i < HW; i += 256) s += p[i];
  for (int off = 32; off; off >>= 1) s += __shfl_xor(s, off);
  __shared__ float rs[4];
  int wid = t >> 6;
  if ((t & 63) == 0) rs[wid] = s;
  __syncthreads();
  if (t == 0) pool[bc] = (rs[0] + rs[1] + rs[2] + rs[3]) * (1.f / 4096.f);
}

// ---------------- gating head: fc -> BN1d -> relu -> softmax -> combine ----------------
__global__ __launch_bounds__(256) void k_head(const float* __restrict__ pool,
    const float* __restrict__ fcw, const float* __restrict__ fcb,
    const float* __restrict__ bg, const float* __restrict__ bb,
    const float* __restrict__ lx, const float* __restrict__ ly,
    float* __restrict__ outLogit) {
  __shared__ float fv[8][2];
  __shared__ float gate[8][2];
  int t = threadIdx.x;
  if (t < 16) {
    int b = t >> 1, k = t & 1;
    float s = fcb[k];
    for (int c = 0; c < 64; ++c) s += pool[b * 64 + c] * fcw[k * 64 + c];
    fv[b][k] = s;
  }
  __syncthreads();
  if (t < 2) {
    float m = 0.f;
    for (int b = 0; b < 8; ++b) m += fv[b][t];
    m *= 0.125f;
    float v = 0.f;
    for (int b = 0; b < 8; ++b) { float d = fv[b][t] - m; v += d * d; }
    v *= 0.125f;
    float is = rsqrtf(v + 1e-5f);
    for (int b = 0; b < 8; ++b) gate[b][t] = bg[t] * (fv[b][t] - m) * is + bb[t];
  }
  __syncthreads();
  if (t < 8) {
    float a = fmaxf(gate[t][0], 0.f), b2 = fmaxf(gate[t][1], 0.f);
    float mx = fmaxf(a, b2);
    float e0 = __expf(a - mx), e1 = __expf(b2 - mx);
    float inv = 1.f / (e0 + e1);
    gate[t][0] = e0 * inv;
    gate[t][1] = e1 * inv;
  }
  __syncthreads();
  for (int i = t; i < 800; i += 256) {
    int b = i / 100;
    outLogit[i] = gate[b][0] * lx[i] + gate[b][1] * ly[i];
  }
}

extern "C" void kernel_launch(void* const* d_in, const int* in_sizes, int n_in,
                              void* d_out, int out_size, void* d_ws, size_t ws_size,
                              hipStream_t stream) {
  (void)in_sizes; (void)n_in; (void)out_size; (void)ws_size;
  const float* x = (const float*)d_in[0];
  const float* y = (const float*)d_in[1];
  const float* logitx = (const float*)d_in[2];
  const float* logity = (const float*)d_in[3];
  const float* conv1_w = (const float*)d_in[4];
  const float* conv1_b = (const float*)d_in[5];
  const float* bn1_g = (const float*)d_in[6];
  const float* bn1_b = (const float*)d_in[7];
  const float* phi_w = (const float*)d_in[8];
  const float* theta_w = (const float*)d_in[9];
  const float* g_w = (const float*)d_in[10];
  const float* mask_w = (const float*)d_in[11];
  const float* fc_w = (const float*)d_in[12];
  const float* fc_b = (const float*)d_in[13];
  const float* bnv_g = (const float*)d_in[14];
  const float* bnv_b = (const float*)d_in[15];

  float* ws = (float*)d_ws;
  float* phi = ws;                    // 8*32*4096 = 1048576
  float* theta = ws + 1048576;        // 1048576
  float* gbuf = ws + 2097152;         // 1048576
  float* obuf = ws + 3145728;         // 1048576
  float* rcs = ws + 4194304;          // 16384
  float* meanp = ws + 4210688;        // 64
  float* istdp = ws + 4210752;        // 64
  float* pool = ws + 4210816;         // 512

  float* zout = (float*)d_out;        // z, then feasc in-place (2097152 floats)
  float* lout = zout + 2097152;       // logit (800 floats)

  k_conv1<<<128, 256, 0, stream>>>(x, y, conv1_w, conv1_b, zout);
  k_bnstats<<<64, 256, 0, stream>>>(zout, meanp, istdp);
  k_proj<<<128, 256, 0, stream>>>(zout, phi_w, theta_w, g_w, meanp, istdp,
                                  bn1_g, bn1_b, phi, theta, gbuf);
  k_colsum<<<256, 256, 0, stream>>>(phi, theta, rcs);
  k_pv<<<256, 256, 0, stream>>>(phi, theta, gbuf, rcs, obuf);
  k_mask<<<128, 256, 0, stream>>>(obuf, mask_w, meanp, istdp, bn1_g, bn1_b, zout);
  k_pool<<<512, 256, 0, stream>>>(zout, pool);
  k_head<<<1, 256, 0, stream>>>(pool, fc_w, fc_b, bnv_g, bnv_b, logitx, logity, lout);
}

// Round 2
// 288.942 us; speedup vs baseline: 2.1496x; 2.1496x over previous
//
#include <hip/hip_runtime.h>

#define CH 64
#define HW 4096
#define NN 2048

typedef __attribute__((ext_vector_type(8))) short bf8_t;
typedef __attribute__((ext_vector_type(4))) float f4_t;
#define MFMA16 __builtin_amdgcn_mfma_f32_16x16x32_bf16

static __device__ inline unsigned short f2bf(float f) {
  union { float f; unsigned u; } v; v.f = f;
  unsigned r = v.u + 0x7fff + ((v.u >> 16) & 1);
  return (unsigned short)(r >> 16);
}

// ---------------- conv1 (128->64 1x1) + bias -> z ----------------
__global__ __launch_bounds__(256) void k_conv1(const float* __restrict__ x,
    const float* __restrict__ y, const float* __restrict__ w,
    const float* __restrict__ bias, float* __restrict__ z) {
  __shared__ float wl[128][64];  // [c][o]
  int t = threadIdx.x;
  for (int i = t; i < 8192; i += 256) { int o = i >> 7, c = i & 127; wl[c][o] = w[i]; }
  __syncthreads();
  int blk = blockIdx.x; int b = blk >> 4; int s = ((blk & 15) << 8) + t;
  const float* xb = x + b * (CH * HW) + s;
  const float* yb = y + b * (CH * HW) + s;
  float acc[64];
#pragma unroll
  for (int o = 0; o < 64; ++o) acc[o] = 0.f;
  for (int c = 0; c < 64; ++c) {
    float xv = xb[c * HW];
    float yv = yb[c * HW];
    const float4* wx = reinterpret_cast<const float4*>(&wl[c][0]);
    const float4* wy = reinterpret_cast<const float4*>(&wl[c + 64][0]);
#pragma unroll
    for (int o4 = 0; o4 < 16; ++o4) {
      float4 a = wx[o4], bb = wy[o4];
      acc[4 * o4 + 0] += xv * a.x + yv * bb.x;
      acc[4 * o4 + 1] += xv * a.y + yv * bb.y;
      acc[4 * o4 + 2] += xv * a.z + yv * bb.z;
      acc[4 * o4 + 3] += xv * a.w + yv * bb.w;
    }
  }
  float* zb = z + b * (CH * HW) + s;
#pragma unroll
  for (int o = 0; o < 64; ++o) zb[o * HW] = acc[o] + bias[o];
}

// ---------------- BN2d stats per channel ----------------
__global__ __launch_bounds__(256) void k_bnstats(const float* __restrict__ z,
    float* __restrict__ meanp, float* __restrict__ istdp) {
  int c = blockIdx.x;
  int t = threadIdx.x;
  float s = 0.f, s2 = 0.f;
  for (int b = 0; b < 8; ++b) {
    const float* p = z + b * (CH * HW) + c * HW;
    for (int i = t; i < HW; i += 256) { float v = p[i]; s += v; s2 += v * v; }
  }
  for (int off = 32; off; off >>= 1) { s += __shfl_xor(s, off); s2 += __shfl_xor(s2, off); }
  __shared__ float rs[4], rs2[4];
  int wid = t >> 6;
  if ((t & 63) == 0) { rs[wid] = s; rs2[wid] = s2; }
  __syncthreads();
  if (t == 0) {
    float S = rs[0] + rs[1] + rs[2] + rs[3];
    float S2 = rs2[0] + rs2[1] + rs2[2] + rs2[3];
    float mean = S / 32768.f;
    float var = S2 / 32768.f - mean * mean;
    meanp[c] = mean;
    istdp[c] = rsqrtf(var + 1e-5f);
  }
}

// ---------------- phi/theta/g projections (BN folded), bf16 MFMA layouts ----------------
// thetaT[n][c~], phiT[m][c~] with c~ = hi*32+ic ; gB[c][m] with c = 2*ic+hi (true c)
__global__ __launch_bounds__(256) void k_proj(const float* __restrict__ z,
    const float* __restrict__ phw, const float* __restrict__ thw,
    const float* __restrict__ gw, const float* __restrict__ meanp,
    const float* __restrict__ istdp, const float* __restrict__ g1,
    const float* __restrict__ b1, unsigned short* __restrict__ phiT,
    unsigned short* __restrict__ thetaT, unsigned short* __restrict__ gB) {
  __shared__ float effw[3][64][32];  // [p][c][ic]
  __shared__ float effb[3][32];
  __shared__ float sc[64], sh[64];
  int t = threadIdx.x;
  if (t < 64) { float s_ = g1[t] * istdp[t]; sc[t] = s_; sh[t] = b1[t] - meanp[t] * s_; }
  __syncthreads();
  for (int i = t; i < 3 * 2048; i += 256) {
    int p = i >> 11; int r = i & 2047; int ic = r >> 6; int c = r & 63;
    const float* wp = (p == 0) ? phw : (p == 1) ? thw : gw;
    effw[p][c][ic] = wp[ic * 64 + c] * sc[c];
  }
  if (t < 96) {
    int p = t / 32, ic = t % 32;
    const float* wp = (p == 0) ? phw : (p == 1) ? thw : gw;
    float s_ = 0.f;
    for (int c = 0; c < 64; ++c) s_ += wp[ic * 64 + c] * sh[c];
    effb[p][ic] = s_;
  }
  __syncthreads();
  int blk = blockIdx.x; int b = blk >> 4; int s = ((blk & 15) << 8) + t;
  int n = s & 2047, hi = s >> 11;
  const float* zb = z + b * (CH * HW) + s;
  for (int p = 0; p < 3; ++p) {
    float acc[32];
#pragma unroll
    for (int ic = 0; ic < 32; ++ic) acc[ic] = effb[p][ic];
    for (int c = 0; c < 64; ++c) {
      float v = zb[c * HW];
      const float4* w4 = reinterpret_cast<const float4*>(&effw[p][c][0]);
#pragma unroll
      for (int q = 0; q < 8; ++q) {
        float4 wv = w4[q];
        acc[4 * q + 0] += v * wv.x;
        acc[4 * q + 1] += v * wv.y;
        acc[4 * q + 2] += v * wv.z;
        acc[4 * q + 3] += v * wv.w;
      }
    }
    if (p < 2) {
      unsigned short* ob = (p == 0 ? phiT : thetaT) + b * (NN * 64) + n * 64 + hi * 32;
      unsigned int pk[16];
#pragma unroll
      for (int q = 0; q < 16; ++q)
        pk[q] = (unsigned int)f2bf(acc[2 * q]) | ((unsigned int)f2bf(acc[2 * q + 1]) << 16);
      uint4* o4 = reinterpret_cast<uint4*>(ob);
#pragma unroll
      for (int q = 0; q < 4; ++q)
        o4[q] = make_uint4(pk[4 * q], pk[4 * q + 1], pk[4 * q + 2], pk[4 * q + 3]);
    } else {
      unsigned short* ob = gB + b * (64 * NN) + n;
#pragma unroll
      for (int ic = 0; ic < 32; ++ic) ob[(2 * ic + hi) * NN] = f2bf(acc[ic]);
    }
  }
}

// ---------------- pass A: rcs[m] = 1 / sum_n exp(S[n,m])  (MFMA) ----------------
__global__ __launch_bounds__(256) void k_colsum(const unsigned short* __restrict__ thetaT,
    const unsigned short* __restrict__ phiT, float* __restrict__ rcs) {
  int blk = blockIdx.x; int b = blk >> 5; int m0 = (blk & 31) << 6;
  int t = threadIdx.x; int lane = t & 63; int w = t >> 6;
  const unsigned short* pT = phiT + b * (NN * 64);
  const unsigned short* tT = thetaT + b * (NN * 64);
  int l15 = lane & 15, lg = lane >> 4;
  bf8_t bf[4][2];
#pragma unroll
  for (int mt = 0; mt < 4; ++mt)
#pragma unroll
    for (int kh = 0; kh < 2; ++kh)
      bf[mt][kh] = *(const bf8_t*)(pT + (m0 + 16 * mt + l15) * 64 + kh * 32 + lg * 8);
  float csum[4] = {0.f, 0.f, 0.f, 0.f};
  for (int nt = 0; nt < 32; ++nt) {
    int nrow = nt * 64 + w * 16 + l15;
    bf8_t a0 = *(const bf8_t*)(tT + nrow * 64 + lg * 8);
    bf8_t a1 = *(const bf8_t*)(tT + nrow * 64 + 32 + lg * 8);
#pragma unroll
    for (int mt = 0; mt < 4; ++mt) {
      f4_t d = {0.f, 0.f, 0.f, 0.f};
      d = MFMA16(a0, bf[mt][0], d, 0, 0, 0);
      d = MFMA16(a1, bf[mt][1], d, 0, 0, 0);
      csum[mt] += __expf(d[0]) + __expf(d[1]) + __expf(d[2]) + __expf(d[3]);
    }
  }
  __shared__ float red[4][4][16];  // [w][mt][col]
#pragma unroll
  for (int mt = 0; mt < 4; ++mt) {
    float v = csum[mt];
    v += __shfl_xor(v, 16);
    v += __shfl_xor(v, 32);
    if (lane < 16) red[w][mt][lane] = v;
  }
  __syncthreads();
  if (t < 64) {
    int mt = t >> 4, col = t & 15;
    float s = red[0][mt][col] + red[1][mt][col] + red[2][mt][col] + red[3][mt][col];
    rcs[b * NN + m0 + mt * 16 + col] = 1.0f / s;
  }
}

// ---------------- pass B: O[n][c] = sum_m exp(S[n,m])*rcs[m]*g[m][c]  (MFMA) ----------------
__global__ __launch_bounds__(256) void k_pv(const unsigned short* __restrict__ thetaT,
    const unsigned short* __restrict__ phiT, const unsigned short* __restrict__ gB,
    const float* __restrict__ rcs, float* __restrict__ obuf) {
  int blk = blockIdx.x; int b = blk >> 5; int n0 = (blk & 31) << 6;
  int t = threadIdx.x; int lane = t & 63; int w = t >> 6;
  int l15 = lane & 15, lg = lane >> 4;
  const unsigned short* tT = thetaT + b * (NN * 64);
  const unsigned short* pT = phiT + b * (NN * 64);
  const unsigned short* gb = gB + b * (64 * NN);
  const float* rb = rcs + b * NN;
  __shared__ unsigned short P_lds[64][72];
  // theta A-frags for this wave's 16 rows (fixed all loop)
  int nrow = n0 + 16 * w + l15;
  bf8_t at0 = *(const bf8_t*)(tT + nrow * 64 + lg * 8);
  bf8_t at1 = *(const bf8_t*)(tT + nrow * 64 + 32 + lg * 8);
  f4_t oacc[4];
#pragma unroll
  for (int ct = 0; ct < 4; ++ct) oacc[ct] = (f4_t){0.f, 0.f, 0.f, 0.f};
  for (int mi = 0; mi < 32; ++mi) {
    int m0 = mi << 6;
    // S tile: 4 col-tiles
    f4_t sfr[4];
#pragma unroll
    for (int mt = 0; mt < 4; ++mt) {
      bf8_t b0 = *(const bf8_t*)(pT + (m0 + 16 * mt + l15) * 64 + lg * 8);
      bf8_t b1 = *(const bf8_t*)(pT + (m0 + 16 * mt + l15) * 64 + 32 + lg * 8);
      f4_t d = {0.f, 0.f, 0.f, 0.f};
      d = MFMA16(at0, b0, d, 0, 0, 0);
      d = MFMA16(at1, b1, d, 0, 0, 0);
      sfr[mt] = d;
    }
    __syncthreads();  // previous iter's P_lds reads done
    int prow = 16 * w + lg * 4;
#pragma unroll
    for (int mt = 0; mt < 4; ++mt) {
      float r_ = rb[m0 + 16 * mt + l15];
#pragma unroll
      for (int q = 0; q < 4; ++q)
        P_lds[prow + q][16 * mt + l15] = f2bf(__expf(sfr[mt][q]) * r_);
    }
    __syncthreads();  // P_lds ready
    bf8_t ap0 = *(const bf8_t*)&P_lds[16 * w + l15][lg * 8];
    bf8_t ap1 = *(const bf8_t*)&P_lds[16 * w + l15][32 + lg * 8];
#pragma unroll
    for (int ct = 0; ct < 4; ++ct) {
      bf8_t g0 = *(const bf8_t*)(gb + (16 * ct + l15) * NN + m0 + lg * 8);
      bf8_t g1 = *(const bf8_t*)(gb + (16 * ct + l15) * NN + m0 + 32 + lg * 8);
      oacc[ct] = MFMA16(ap0, g0, oacc[ct], 0, 0, 0);
      oacc[ct] = MFMA16(ap1, g1, oacc[ct], 0, 0, 0);
    }
  }
  float* ob = obuf + b * (32 * HW);
#pragma unroll
  for (int ct = 0; ct < 4; ++ct) {
    int c = 16 * ct + l15;
    int nb = n0 + 16 * w + lg * 4;
    *(f4_t*)(ob + c * NN + nb) = oacc[ct];
  }
}

// ---------------- mask conv (32->64) + BN(z) residual, in-place into d_out ----------------
__global__ __launch_bounds__(256) void k_mask(const float* __restrict__ obuf,
    const float* __restrict__ mw, const float* __restrict__ meanp,
    const float* __restrict__ istdp, const float* __restrict__ g1,
    const float* __restrict__ b1, float* __restrict__ zio) {
  __shared__ float ml_[32][64];  // [ic][oc]
  __shared__ float sc[64], sh[64];
  int t = threadIdx.x;
  for (int i = t; i < 2048; i += 256) { int oc = i >> 5, ic = i & 31; ml_[ic][oc] = mw[i]; }
  if (t < 64) { float s_ = g1[t] * istdp[t]; sc[t] = s_; sh[t] = b1[t] - meanp[t] * s_; }
  __syncthreads();
  int blk = blockIdx.x; int b = blk >> 4; int s = ((blk & 15) << 8) + t;
  const float* ob = obuf + b * (32 * HW) + s;
  float acc[64];
#pragma unroll
  for (int o = 0; o < 64; ++o) acc[o] = 0.f;
  for (int ic = 0; ic < 32; ++ic) {
    float v = ob[ic * HW];
    const float4* w4 = reinterpret_cast<const float4*>(&ml_[ic][0]);
#pragma unroll
    for (int o4 = 0; o4 < 16; ++o4) {
      float4 wv = w4[o4];
      acc[4 * o4 + 0] += v * wv.x;
      acc[4 * o4 + 1] += v * wv.y;
      acc[4 * o4 + 2] += v * wv.z;
      acc[4 * o4 + 3] += v * wv.w;
    }
  }
  float* zb = zio + b * (CH * HW) + s;
#pragma unroll
  for (int oc = 0; oc < 64; ++oc) {
    float zv = zb[oc * HW];
    zb[oc * HW] = acc[oc] + sc[oc] * zv + sh[oc];
  }
}

// ---------------- adaptive avg pool per (b,c) ----------------
__global__ __launch_bounds__(256) void k_pool(const float* __restrict__ feasc,
    float* __restrict__ pool) {
  int bc = blockIdx.x;
  int t = threadIdx.x;
  const float* p = feasc + bc * HW;
  float s = 0.f;
  for (int i = t; i < HW; i += 256) s += p[i];
  for (int off = 32; off; off >>= 1) s += __shfl_xor(s, off);
  __shared__ float rs[4];
  int wid = t >> 6;
  if ((t & 63) == 0) rs[wid] = s;
  __syncthreads();
  if (t == 0) pool[bc] = (rs[0] + rs[1] + rs[2] + rs[3]) * (1.f / 4096.f);
}

// ---------------- gating head ----------------
__global__ __launch_bounds__(256) void k_head(const float* __restrict__ pool,
    const float* __restrict__ fcw, const float* __restrict__ fcb,
    const float* __restrict__ bg, const float* __restrict__ bb,
    const float* __restrict__ lx, const float* __restrict__ ly,
    float* __restrict__ outLogit) {
  __shared__ float fv[8][2];
  __shared__ float gate[8][2];
  int t = threadIdx.x;
  if (t < 16) {
    int b = t >> 1, k = t & 1;
    float s = fcb[k];
    for (int c = 0; c < 64; ++c) s += pool[b * 64 + c] * fcw[k * 64 + c];
    fv[b][k] = s;
  }
  __syncthreads();
  if (t < 2) {
    float m = 0.f;
    for (int b = 0; b < 8; ++b) m += fv[b][t];
    m *= 0.125f;
    float v = 0.f;
    for (int b = 0; b < 8; ++b) { float d = fv[b][t] - m; v += d * d; }
    v *= 0.125f;
    float is = rsqrtf(v + 1e-5f);
    for (int b = 0; b < 8; ++b) gate[b][t] = bg[t] * (fv[b][t] - m) * is + bb[t];
  }
  __syncthreads();
  if (t < 8) {
    float a = fmaxf(gate[t][0], 0.f), b2 = fmaxf(gate[t][1], 0.f);
    float mx = fmaxf(a, b2);
    float e0 = __expf(a - mx), e1 = __expf(b2 - mx);
    float inv = 1.f / (e0 + e1);
    gate[t][0] = e0 * inv;
    gate[t][1] = e1 * inv;
  }
  __syncthreads();
  for (int i = t; i < 800; i += 256) {
    int b = i / 100;
    outLogit[i] = gate[b][0] * lx[i] + gate[b][1] * ly[i];
  }
}

extern "C" void kernel_launch(void* const* d_in, const int* in_sizes, int n_in,
                              void* d_out, int out_size, void* d_ws, size_t ws_size,
                              hipStream_t stream) {
  (void)in_sizes; (void)n_in; (void)out_size; (void)ws_size;
  const float* x = (const float*)d_in[0];
  const float* y = (const float*)d_in[1];
  const float* logitx = (const float*)d_in[2];
  const float* logity = (const float*)d_in[3];
  const float* conv1_w = (const float*)d_in[4];
  const float* conv1_b = (const float*)d_in[5];
  const float* bn1_g = (const float*)d_in[6];
  const float* bn1_b = (const float*)d_in[7];
  const float* phi_w = (const float*)d_in[8];
  const float* theta_w = (const float*)d_in[9];
  const float* g_w = (const float*)d_in[10];
  const float* mask_w = (const float*)d_in[11];
  const float* fc_w = (const float*)d_in[12];
  const float* fc_b = (const float*)d_in[13];
  const float* bnv_g = (const float*)d_in[14];
  const float* bnv_b = (const float*)d_in[15];

  char* ws = (char*)d_ws;
  unsigned short* thetaT = (unsigned short*)(ws);                 // 2 MB
  unsigned short* phiT   = (unsigned short*)(ws + (2u << 20));    // 2 MB
  unsigned short* gB     = (unsigned short*)(ws + (4u << 20));    // 2 MB
  float* obuf            = (float*)(ws + (6u << 20));             // 4 MB
  float* rcs             = (float*)(ws + (10u << 20));            // 64 KB
  float* meanp           = (float*)(ws + (11u << 20));
  float* istdp           = meanp + 64;
  float* pool            = istdp + 64;

  float* zout = (float*)d_out;        // z, then feasc in-place (2097152 floats)
  float* lout = zout + 2097152;       // logit (800 floats)

  k_conv1<<<128, 256, 0, stream>>>(x, y, conv1_w, conv1_b, zout);
  k_bnstats<<<64, 256, 0, stream>>>(zout, meanp, istdp);
  k_proj<<<128, 256, 0, stream>>>(zout, phi_w, theta_w, g_w, meanp, istdp,
                                  bn1_g, bn1_b, phiT, thetaT, gB);
  k_colsum<<<256, 256, 0, stream>>>(thetaT, phiT, rcs);
  k_pv<<<256, 256, 0, stream>>>(thetaT, phiT, gB, rcs, obuf);
  k_mask<<<128, 256, 0, stream>>>(obuf, mask_w, meanp, istdp, bn1_g, bn1_b, zout);
  k_pool<<<512, 256, 0, stream>>>(zout, pool);
  k_head<<<1, 256, 0, stream>>>(pool, fc_w, fc_b, bnv_g, bnv_b, logitx, logity, lout);
}

// Round 3
// 204.609 us; speedup vs baseline: 3.0356x; 1.4122x over previous
//
#include <hip/hip_runtime.h>

#define CH 64
#define HW 4096
#define NN 2048

typedef __attribute__((ext_vector_type(8))) short bf8_t;
typedef __attribute__((ext_vector_type(4))) float f4_t;
#define MFMA16 __builtin_amdgcn_mfma_f32_16x16x32_bf16

static __device__ inline unsigned short f2bf(float f) {
  union { float f; unsigned u; } v; v.f = f;
  unsigned r = v.u + 0x7fff + ((v.u >> 16) & 1);
  return (unsigned short)(r >> 16);
}
static __device__ inline float bf2f(unsigned short u) {
  union { unsigned u; float f; } v; v.u = ((unsigned)u) << 16;
  return v.f;
}

// ---------- conv1 (128->64) + bias -> z, fused BN partial sums ----------
// grid (128, 2): x = position chunk (b*16+ch), y = output half
__global__ __launch_bounds__(256) void k_conv1(const float* __restrict__ x,
    const float* __restrict__ y, const float* __restrict__ w,
    const float* __restrict__ bias, float* __restrict__ z,
    float2* __restrict__ partials) {
  __shared__ float wl[128][32];  // [c][o]  (this y-half's 32 outputs)
  __shared__ float redS[4][32], redQ[4][32];
  int t = threadIdx.x;
  int yh = blockIdx.y;
  int bx = blockIdx.x;
  for (int i = t; i < 4096; i += 256) {
    int o = i & 31, c = i >> 5;
    wl[c][o] = w[(yh * 32 + o) * 128 + c];
  }
  __syncthreads();
  int b = bx >> 4;
  int s = ((bx & 15) << 8) + t;
  const float* xb = x + b * (CH * HW) + s;
  const float* yb = y + b * (CH * HW) + s;
  float acc[32];
#pragma unroll
  for (int o = 0; o < 32; ++o) acc[o] = 0.f;
  for (int c = 0; c < 64; ++c) {
    float xv = xb[c * HW];
    float yv = yb[c * HW];
    const float4* wx = reinterpret_cast<const float4*>(&wl[c][0]);
    const float4* wy = reinterpret_cast<const float4*>(&wl[c + 64][0]);
#pragma unroll
    for (int o4 = 0; o4 < 8; ++o4) {
      float4 a = wx[o4], bb = wy[o4];
      acc[4 * o4 + 0] += xv * a.x + yv * bb.x;
      acc[4 * o4 + 1] += xv * a.y + yv * bb.y;
      acc[4 * o4 + 2] += xv * a.z + yv * bb.z;
      acc[4 * o4 + 3] += xv * a.w + yv * bb.w;
    }
  }
  float* zb = z + b * (CH * HW) + s;
  int lane = t & 63, wv = t >> 6;
#pragma unroll
  for (int o = 0; o < 32; ++o) {
    float v = acc[o] + bias[yh * 32 + o];
    zb[(yh * 32 + o) * HW] = v;
    float a1 = v, a2 = v * v;
    for (int off = 32; off; off >>= 1) {
      a1 += __shfl_xor(a1, off);
      a2 += __shfl_xor(a2, off);
    }
    if (lane == 0) { redS[wv][o] = a1; redQ[wv][o] = a2; }
  }
  __syncthreads();
  if (t < 32) {
    float2 pp;
    pp.x = redS[0][t] + redS[1][t] + redS[2][t] + redS[3][t];
    pp.y = redQ[0][t] + redQ[1][t] + redQ[2][t] + redQ[3][t];
    partials[((bx << 1) + yh) * 32 + t] = pp;
  }
}

// ---------- prep: reduce BN stats, fold weights ----------
__global__ __launch_bounds__(256) void k_prep1(const float2* __restrict__ partials,
    const float* __restrict__ phw, const float* __restrict__ thw,
    const float* __restrict__ gw, const float* __restrict__ mask_w,
    const float* __restrict__ g1, const float* __restrict__ b1,
    float* __restrict__ effw, float* __restrict__ effb,
    float* __restrict__ wM, float* __restrict__ scA, float* __restrict__ shA) {
  __shared__ float scS[64], shS[64];
  int t = threadIdx.x;
  if (t < 64) {
    int yh = t >> 5, o = t & 31;
    float S = 0.f, S2 = 0.f;
    for (int cb = 0; cb < 128; ++cb) {
      float2 p = partials[((cb << 1) + yh) * 32 + o];
      S += p.x; S2 += p.y;
    }
    float mean = S * (1.f / 32768.f);
    float var = S2 * (1.f / 32768.f) - mean * mean;
    float is = rsqrtf(var + 1e-5f);
    float sc = g1[t] * is;
    float sh = b1[t] - mean * sc;
    scS[t] = sc; shS[t] = sh;
    scA[t] = sc; shA[t] = sh;
  }
  __syncthreads();
  for (int i = t; i < 6144; i += 256) {
    int p = i >> 11, c = (i >> 5) & 63, ic = i & 31;
    const float* wp = (p == 0) ? phw : (p == 1) ? thw : gw;
    effw[i] = wp[ic * 64 + c] * scS[c];
  }
  for (int i = t; i < 2048; i += 256) {
    int ic = i >> 6, oc = i & 63;
    wM[i] = mask_w[oc * 32 + ic];
  }
  if (t < 96) {
    int p = t >> 5, ic = t & 31;
    const float* wp = (p == 0) ? phw : (p == 1) ? thw : gw;
    float s_ = 0.f;
    for (int c = 0; c < 64; ++c) s_ += wp[ic * 64 + c] * shS[c];
    effb[t] = s_;
  }
}

// ---------- projections: grid (128, 3), y = which projection ----------
__global__ __launch_bounds__(256) void k_proj(const float* __restrict__ z,
    const float* __restrict__ effw, const float* __restrict__ effb,
    unsigned short* __restrict__ phiT, unsigned short* __restrict__ thetaT,
    unsigned short* __restrict__ gB) {
  int t = threadIdx.x;
  int p = blockIdx.y;
  int bx = blockIdx.x;
  int b = bx >> 4;
  int s = ((bx & 15) << 8) + t;
  int n = s & 2047, hi = s >> 11;
  const float* zb = z + b * (CH * HW) + s;
  const float* wp = effw + p * 2048;
  float acc[32];
#pragma unroll
  for (int ic = 0; ic < 32; ++ic) acc[ic] = effb[p * 32 + ic];
  for (int c = 0; c < 64; ++c) {
    float v = zb[c * HW];
    const float4* w4 = reinterpret_cast<const float4*>(wp + c * 32);
#pragma unroll
    for (int q = 0; q < 8; ++q) {
      float4 wv = w4[q];
      acc[4 * q + 0] += v * wv.x;
      acc[4 * q + 1] += v * wv.y;
      acc[4 * q + 2] += v * wv.z;
      acc[4 * q + 3] += v * wv.w;
    }
  }
  if (p < 2) {
    unsigned short* ob = (p == 0 ? phiT : thetaT) + b * (NN * 64) + n * 64 + hi * 32;
    unsigned int pk[16];
#pragma unroll
    for (int q = 0; q < 16; ++q)
      pk[q] = (unsigned int)f2bf(acc[2 * q]) | ((unsigned int)f2bf(acc[2 * q + 1]) << 16);
    uint4* o4 = reinterpret_cast<uint4*>(ob);
#pragma unroll
    for (int q = 0; q < 4; ++q)
      o4[q] = make_uint4(pk[4 * q], pk[4 * q + 1], pk[4 * q + 2], pk[4 * q + 3]);
  } else {
    unsigned short* ob = gB + b * (64 * NN) + n;
#pragma unroll
    for (int ic = 0; ic < 32; ++ic) ob[(2 * ic + hi) * NN] = f2bf(acc[ic]);
  }
}

// ---------- pass A: partial column sums of exp(S); grid (64, 8) ----------
// x = mtile*2 + nhalf, y = b. csum[b][nhalf][2048]
__global__ __launch_bounds__(256) void k_colsum(const unsigned short* __restrict__ thetaT,
    const unsigned short* __restrict__ phiT, float* __restrict__ csum) {
  int bx = blockIdx.x;
  int b = blockIdx.y;
  int mtile = bx >> 1, nhalf = bx & 1;
  int m0 = mtile << 6;
  int t = threadIdx.x; int lane = t & 63; int w = t >> 6;
  const unsigned short* pT = phiT + b * (NN * 64);
  const unsigned short* tT = thetaT + b * (NN * 64);
  int l15 = lane & 15, lg = lane >> 4;
  bf8_t bf[4][2];
#pragma unroll
  for (int mt = 0; mt < 4; ++mt)
#pragma unroll
    for (int kh = 0; kh < 2; ++kh)
      bf[mt][kh] = *(const bf8_t*)(pT + (m0 + 16 * mt + l15) * 64 + kh * 32 + lg * 8);
  float cs[4] = {0.f, 0.f, 0.f, 0.f};
  for (int nt = nhalf * 16; nt < nhalf * 16 + 16; ++nt) {
    int nrow = nt * 64 + w * 16 + l15;
    bf8_t a0 = *(const bf8_t*)(tT + nrow * 64 + lg * 8);
    bf8_t a1 = *(const bf8_t*)(tT + nrow * 64 + 32 + lg * 8);
#pragma unroll
    for (int mt = 0; mt < 4; ++mt) {
      f4_t d = {0.f, 0.f, 0.f, 0.f};
      d = MFMA16(a0, bf[mt][0], d, 0, 0, 0);
      d = MFMA16(a1, bf[mt][1], d, 0, 0, 0);
      cs[mt] += __expf(d[0]) + __expf(d[1]) + __expf(d[2]) + __expf(d[3]);
    }
  }
  __shared__ float red[4][4][16];
#pragma unroll
  for (int mt = 0; mt < 4; ++mt) {
    float v = cs[mt];
    v += __shfl_xor(v, 16);
    v += __shfl_xor(v, 32);
    if (lane < 16) red[w][mt][lane] = v;
  }
  __syncthreads();
  if (t < 64) {
    int mt = t >> 4, col = t & 15;
    float s = red[0][mt][col] + red[1][mt][col] + red[2][mt][col] + red[3][mt][col];
    csum[b * 4096 + nhalf * 2048 + m0 + mt * 16 + col] = s;
  }
}

// ---------- pass B: O half-sums (bf16); grid (64, 8) ----------
// x = ntile*2 + mhalf, y = b. obufH[mhalf][b][32c][4096]
__global__ __launch_bounds__(256) void k_pv(const unsigned short* __restrict__ thetaT,
    const unsigned short* __restrict__ phiT, const unsigned short* __restrict__ gB,
    const float* __restrict__ csum, unsigned short* __restrict__ obufH) {
  int bx = blockIdx.x;
  int b = blockIdx.y;
  int ntile = bx >> 1, mhalf = bx & 1;
  int n0 = ntile << 6;
  int t = threadIdx.x; int lane = t & 63; int w = t >> 6;
  int l15 = lane & 15, lg = lane >> 4;
  const unsigned short* tT = thetaT + b * (NN * 64);
  const unsigned short* pT = phiT + b * (NN * 64);
  const unsigned short* gb = gB + b * (64 * NN);
  const float* cs0 = csum + b * 4096;
  __shared__ unsigned short P_lds[64][72];
  int nrow = n0 + 16 * w + l15;
  bf8_t at0 = *(const bf8_t*)(tT + nrow * 64 + lg * 8);
  bf8_t at1 = *(const bf8_t*)(tT + nrow * 64 + 32 + lg * 8);
  f4_t oacc[4];
#pragma unroll
  for (int ct = 0; ct < 4; ++ct) oacc[ct] = (f4_t){0.f, 0.f, 0.f, 0.f};
  for (int mi = mhalf * 16; mi < mhalf * 16 + 16; ++mi) {
    int m0 = mi << 6;
    f4_t sfr[4];
#pragma unroll
    for (int mt = 0; mt < 4; ++mt) {
      bf8_t b0 = *(const bf8_t*)(pT + (m0 + 16 * mt + l15) * 64 + lg * 8);
      bf8_t b1 = *(const bf8_t*)(pT + (m0 + 16 * mt + l15) * 64 + 32 + lg * 8);
      f4_t d = {0.f, 0.f, 0.f, 0.f};
      d = MFMA16(at0, b0, d, 0, 0, 0);
      d = MFMA16(at1, b1, d, 0, 0, 0);
      sfr[mt] = d;
    }
    __syncthreads();
    int prow = 16 * w + lg * 4;
#pragma unroll
    for (int mt = 0; mt < 4; ++mt) {
      int m = m0 + 16 * mt + l15;
      float r_ = 1.0f / (cs0[m] + cs0[2048 + m]);
#pragma unroll
      for (int q = 0; q < 4; ++q)
        P_lds[prow + q][16 * mt + l15] = f2bf(__expf(sfr[mt][q]) * r_);
    }
    __syncthreads();
    bf8_t ap0 = *(const bf8_t*)&P_lds[16 * w + l15][lg * 8];
    bf8_t ap1 = *(const bf8_t*)&P_lds[16 * w + l15][32 + lg * 8];
#pragma unroll
    for (int ct = 0; ct < 4; ++ct) {
      bf8_t g0 = *(const bf8_t*)(gb + (16 * ct + l15) * NN + m0 + lg * 8);
      bf8_t g1 = *(const bf8_t*)(gb + (16 * ct + l15) * NN + m0 + 32 + lg * 8);
      oacc[ct] = MFMA16(ap0, g0, oacc[ct], 0, 0, 0);
      oacc[ct] = MFMA16(ap1, g1, oacc[ct], 0, 0, 0);
    }
  }
  unsigned short* ob = obufH + mhalf * 1048576 + b * (32 * HW);
#pragma unroll
  for (int ct = 0; ct < 4; ++ct) {
    int c = 16 * ct + l15;
    int nb = n0 + 16 * w + lg * 4;
    unsigned p0 = (unsigned)f2bf(oacc[ct][0]) | ((unsigned)f2bf(oacc[ct][1]) << 16);
    unsigned p1 = (unsigned)f2bf(oacc[ct][2]) | ((unsigned)f2bf(oacc[ct][3]) << 16);
    uint2 pk; pk.x = p0; pk.y = p1;
    *reinterpret_cast<uint2*>(ob + c * NN + nb) = pk;
  }
}

// ---------- mask conv + residual + pool partials; grid (128, 2) ----------
__global__ __launch_bounds__(256) void k_mask(const unsigned short* __restrict__ obufH,
    const float* __restrict__ wM, const float* __restrict__ scA,
    const float* __restrict__ shA, float* __restrict__ zio,
    float* __restrict__ poolpart) {
  __shared__ float red[4][32];
  int t = threadIdx.x;
  int yh = blockIdx.y;
  int bx = blockIdx.x;
  int b = bx >> 4;
  int s = ((bx & 15) << 8) + t;
  float acc[32];
#pragma unroll
  for (int o = 0; o < 32; ++o) acc[o] = 0.f;
  for (int ic = 0; ic < 32; ++ic) {
    int idx = b * (32 * HW) + ic * HW + s;
    float v = bf2f(obufH[idx]) + bf2f(obufH[1048576 + idx]);
    const float4* w4 = reinterpret_cast<const float4*>(wM + ic * 64 + yh * 32);
#pragma unroll
    for (int q = 0; q < 8; ++q) {
      float4 wv = w4[q];
      acc[4 * q + 0] += v * wv.x;
      acc[4 * q + 1] += v * wv.y;
      acc[4 * q + 2] += v * wv.z;
      acc[4 * q + 3] += v * wv.w;
    }
  }
  float* zb = zio + b * (CH * HW) + s;
  int lane = t & 63, wv_ = t >> 6;
#pragma unroll
  for (int o = 0; o < 32; ++o) {
    int oc = yh * 32 + o;
    float zv = zb[oc * HW];
    float r = acc[o] + scA[oc] * zv + shA[oc];
    zb[oc * HW] = r;
    for (int off = 32; off; off >>= 1) r += __shfl_xor(r, off);
    if (lane == 0) red[wv_][o] = r;
  }
  __syncthreads();
  if (t < 32)
    poolpart[((bx << 1) + yh) * 32 + t] =
        red[0][t] + red[1][t] + red[2][t] + red[3][t];
}

// ---------- head: pool reduce + fc + BN1d + relu + softmax + combine ----------
__global__ __launch_bounds__(256) void k_head(const float* __restrict__ poolpart,
    const float* __restrict__ fcw, const float* __restrict__ fcb,
    const float* __restrict__ bg, const float* __restrict__ bb,
    const float* __restrict__ lx, const float* __restrict__ ly,
    float* __restrict__ outLogit) {
  __shared__ float poolS[8][64];
  __shared__ float fv[8][2];
  __shared__ float gate[8][2];
  int t = threadIdx.x;
  for (int idx = t; idx < 512; idx += 256) {
    int b = idx >> 6, oc = idx & 63;
    int yh = oc >> 5, o = oc & 31;
    float s = 0.f;
    for (int ch = 0; ch < 16; ++ch)
      s += poolpart[((((b << 4) + ch) << 1) + yh) * 32 + o];
    poolS[b][oc] = s * (1.f / 4096.f);
  }
  __syncthreads();
  if (t < 16) {
    int b = t >> 1, k = t & 1;
    float s = fcb[k];
    for (int c = 0; c < 64; ++c) s += poolS[b][c] * fcw[k * 64 + c];
    fv[b][k] = s;
  }
  __syncthreads();
  if (t < 2) {
    float m = 0.f;
    for (int b = 0; b < 8; ++b) m += fv[b][t];
    m *= 0.125f;
    float v = 0.f;
    for (int b = 0; b < 8; ++b) { float d = fv[b][t] - m; v += d * d; }
    v *= 0.125f;
    float is = rsqrtf(v + 1e-5f);
    for (int b = 0; b < 8; ++b) gate[b][t] = bg[t] * (fv[b][t] - m) * is + bb[t];
  }
  __syncthreads();
  if (t < 8) {
    float a = fmaxf(gate[t][0], 0.f), b2 = fmaxf(gate[t][1], 0.f);
    float mx = fmaxf(a, b2);
    float e0 = __expf(a - mx), e1 = __expf(b2 - mx);
    float inv = 1.f / (e0 + e1);
    gate[t][0] = e0 * inv;
    gate[t][1] = e1 * inv;
  }
  __syncthreads();
  for (int i = t; i < 800; i += 256) {
    int b = i / 100;
    outLogit[i] = gate[b][0] * lx[i] + gate[b][1] * ly[i];
  }
}

extern "C" void kernel_launch(void* const* d_in, const int* in_sizes, int n_in,
                              void* d_out, int out_size, void* d_ws, size_t ws_size,
                              hipStream_t stream) {
  (void)in_sizes; (void)n_in; (void)out_size; (void)ws_size;
  const float* x = (const float*)d_in[0];
  const float* y = (const float*)d_in[1];
  const float* logitx = (const float*)d_in[2];
  const float* logity = (const float*)d_in[3];
  const float* conv1_w = (const float*)d_in[4];
  const float* conv1_b = (const float*)d_in[5];
  const float* bn1_g = (const float*)d_in[6];
  const float* bn1_b = (const float*)d_in[7];
  const float* phi_w = (const float*)d_in[8];
  const float* theta_w = (const float*)d_in[9];
  const float* g_w = (const float*)d_in[10];
  const float* mask_w = (const float*)d_in[11];
  const float* fc_w = (const float*)d_in[12];
  const float* fc_b = (const float*)d_in[13];
  const float* bnv_g = (const float*)d_in[14];
  const float* bnv_b = (const float*)d_in[15];

  unsigned short* U = (unsigned short*)d_ws;
  float* F = (float*)d_ws;
  unsigned short* thetaT = U;                   // 1,048,576 shorts (2 MB)
  unsigned short* phiT   = U + 1048576;         // 2 MB
  unsigned short* gB     = U + 2097152;         // 2 MB
  unsigned short* obufH  = U + 3145728;         // 2 x 1,048,576 shorts (4 MB)
  float* csum     = F + 2621440;                // 8*4096 floats (128 KB)
  float2* partials = (float2*)(F + 2654208);    // 256*32 float2 (64 KB)
  float* poolpart = F + 2670592;                // 256*32 (32 KB)
  float* effw     = F + 2678784;                // 6144
  float* effb     = F + 2684928;                // 96 (pad 256)
  float* wM       = F + 2685184;                // 2048
  float* scA      = F + 2687232;                // 64
  float* shA      = F + 2687296;                // 64

  float* zout = (float*)d_out;        // z then feasc in-place (2,097,152 floats)
  float* lout = zout + 2097152;       // logit (800 floats)

  k_conv1<<<dim3(128, 2), 256, 0, stream>>>(x, y, conv1_w, conv1_b, zout, partials);
  k_prep1<<<1, 256, 0, stream>>>(partials, phi_w, theta_w, g_w, mask_w,
                                 bn1_g, bn1_b, effw, effb, wM, scA, shA);
  k_proj<<<dim3(128, 3), 256, 0, stream>>>(zout, effw, effb, phiT, thetaT, gB);
  k_colsum<<<dim3(64, 8), 256, 0, stream>>>(thetaT, phiT, csum);
  k_pv<<<dim3(64, 8), 256, 0, stream>>>(thetaT, phiT, gB, csum, obufH);
  k_mask<<<dim3(128, 2), 256, 0, stream>>>(obufH, wM, scA, shA, zout, poolpart);
  k_head<<<1, 256, 0, stream>>>(poolpart, fc_w, fc_b, bnv_g, bnv_b, logitx, logity, lout);
}